// Round 7
// baseline (232.491 us; speedup 1.0000x reference)
//
#include <hip/hip_runtime.h>

// TV-L1 optical flow, B=4, 512x512, 20 iters — temporal blocking (ghost zones)
// R12: R10 base (revert R11's k_statics hoist — it was net -3.8 us) +
// BRANCHLESS PHASE BODIES. R10's phase loops guarded each slot with a
// divergent `continue`, so the compiler emitted per-slot exec-mask regions
// and slot s+1's 4 ds_read_b64 were not issued until slot s completed:
// only ~4 outstanding LDS reads per thread per phase, x ~120cy LDS latency
// x 10 barrier-separated phases = the serialization (R9->R10: +50% waves
// gave only +13%; VALUBusy 30%). Here each phase computes all cone masks
// first, selects a safe interior address for out-of-cone slots (v_cndmask),
// issues ALL slots' loads back-to-back (12 reads in flight in u-phase,
// 6 in p-phase), computes, then masks the writebacks. Out-of-cone lanes
// compute finite garbage that selects discard. ~+30 live VGPRs during the
// load clusters; R10 allocated 52, budget at 6 waves/SIMD is 85.
// Geometry unchanged from R10: T=32, REG=48, TPB=768, SLOTS=3 exact-fit,
// LDS 55.3 KB -> 2 blocks/CU, 6 waves/SIMD. Prologue/epilogue byte-
// identical to R10 (R6-R8 lesson: body perturbations risk IR-level array
// demotion to scratch — watch VGPR_Count and FETCH_SIZE).
//   LDS: su=(u1,u2), spa=(p11,p21), spb=(p12,p22), 3 x 2304 x 8B = 55.3 KB.
// Halo L=6/R=10 (48x48 region per 32x32 tile). Zero-padding reproduced by
// forcing u=p=0 on out-of-image pixels. Last kernel skips the dead 20th
// p-update and fuses the 3x3 avgpool.

#define HH 512
#define WW 512
#define BB 4
constexpr int HW   = HH * WW;
constexpr int NTOT = BB * HW;
constexpr float EPS = 1e-8f;

#define T 32          // output tile edge
#define HALO_L 6      // left/top halo
#define REG 48        // region edge = 32 + 6 + 10
#define NPX (REG * REG)   // 2304
#define TPB 768
#define SLOTS 3       // 768*3 == 2304 exactly
#define NBLK 1024     // 4 images x 16x16 tiles
#define XR 50         // x1 staging edge (region + 1-ring for 3x3 gradient)
#define XN (XR * XR)  // 2500 <= 4608 floats available in spa
#define XSL 4         // ceil(2500/768) staging iterations
#define SAFE_U (REG + 1)  // interior addr for masked-off u-phase reads
#define SAFE_P 0          // safe addr for masked-off p-phase reads (+1,+REG)

// phase: 0 = first (u,p zero-init, write back), 1 = middle (load, write
// back), 2 = last (load, 5 u-phases + 4 p-phases, fused avgpool -> out).
__global__ __launch_bounds__(TPB, 1) void k_fused(
    const float* __restrict__ x,
    float2* __restrict__ ug, float4* __restrict__ pg,
    const float* __restrict__ lam_p, const float* __restrict__ tau_p,
    const float* __restrict__ theta_p,
    const float* __restrict__ wxp, const float* __restrict__ wyp,
    float* __restrict__ out, int phase)
{
    __shared__ float2 su[NPX];    // (u1,u2)
    __shared__ float2 spa[NPX];   // (p11,p21); doubles as x1 staging buffer
    __shared__ float2 spb[NPX];   // (p12,p22)   -> 55.3 KB total

    const int tid  = threadIdx.x;
    const int blk  = blockIdx.x;
    const int bimg = blk >> 8;
    const int t    = blk & 255;
    const int gi0  = (t >> 4) * T;
    const int gj0  = (t & 15) * T;

    const float lam = lam_p[0], theta = theta_p[0];
    const float r   = tau_p[0] / theta;
    const float tl  = theta * lam;
    const float wx0 = wxp[0], wx1 = wxp[1], wx2 = wxp[2];
    const float wy0 = wyp[0], wy1 = wyp[1], wy2 = wyp[2];

    const int gbase = bimg * HW;
    const float* x0p = x + (size_t)bimg * 2 * HW;
    const float* x1p = x0p + HW;

    int  lis[SLOTS], ljs[SLOTS], gofs[SLOTS];
    bool inb[SLOTS];
    float2 ruv[SLOTS], rpa[SLOTS], rpb[SLOTS];  // own-pixel mirrors
    float  x0v[SLOTS];

    // ---- pass 1a: per-slot indices + state loads (issued first) ----------
    #pragma unroll
    for (int s = 0; s < SLOTS; ++s) {
        int idx = tid + s * TPB;                  // < NPX always (768*3=2304)
        int li = idx / REG, lj = idx - li * REG;
        lis[s] = li; ljs[s] = lj;
        int gi = gi0 + li - HALO_L, gj = gj0 + lj - HALO_L;
        bool in = ((unsigned)gi < HH) & ((unsigned)gj < WW);
        inb[s] = in;
        int gl = gi * WW + gj;            // valid only when in
        gofs[s] = gl;
        float2 uv = make_float2(0.f, 0.f);
        float4 p4 = make_float4(0.f, 0.f, 0.f, 0.f);
        float xv = 0.f;
        if (in) {
            xv = x0p[gl];
            if (phase != 0) {
                uv = ug[gbase + gl];
                p4 = pg[gbase + gl];
            }
        }
        x0v[s] = xv;
        ruv[s] = uv;
        rpa[s] = make_float2(p4.x, p4.y);
        rpb[s] = make_float2(p4.z, p4.w);
    }
    // ---- pass 1b: stage x1 into spa-as-float (overlaps 1a's loads) -------
    #pragma unroll
    for (int s = 0; s < XSL; ++s) {
        int idx = tid + s * TPB;
        if (idx < XN) {
            int li = idx / XR, lj = idx - li * XR;
            int gi = gi0 + li - (HALO_L + 1), gj = gj0 + lj - (HALO_L + 1);
            bool in = ((unsigned)gi < HH) & ((unsigned)gj < WW);
            ((float*)spa)[idx] = in ? x1p[gi * WW + gj] : 0.f;
        }
    }
    __syncthreads();

    // ---- pass 2: statics (gx,gy,rc,th,1/nm) from staged x1 ---------------
    float rgx[SLOTS], rgy[SLOTS], rrc[SLOTS], rth[SLOTS], rnv[SLOTS];
    const float* stg = (const float*)spa;
    #pragma unroll
    for (int s = 0; s < SLOTS; ++s) {
        int sc = (lis[s] + 1) * XR + (ljs[s] + 1);
        float a00 = stg[sc - XR - 1], a01 = stg[sc - XR], a02 = stg[sc - XR + 1];
        float a10 = stg[sc - 1],      a11 = stg[sc],      a12 = stg[sc + 1];
        float a20 = stg[sc + XR - 1], a21 = stg[sc + XR], a22 = stg[sc + XR + 1];
        const float c6 = 1.f / 6.f;
        float gxv = c6 * (-a00 + a02 - 2.f * a10 + 2.f * a12 - a20 + a22);
        float gyv = c6 * (-a00 - 2.f * a01 - a02 + a20 + 2.f * a21 + a22);
        float nm  = gxv * gxv + gyv * gyv + EPS;
        rgx[s] = gxv; rgy[s] = gyv;
        rrc[s] = a11 - x0v[s];           // zero-padded conv semantics held
        rth[s] = tl * nm;
        rnv[s] = __builtin_amdgcn_rcpf(nm);
    }
    __syncthreads();

    // ---- pass 3: fill LDS state (overwrites staging) ---------------------
    #pragma unroll
    for (int s = 0; s < SLOTS; ++s) {
        int idx = tid + s * TPB;
        su[idx]  = ruv[s];
        spa[idx] = rpa[s];
        spb[idx] = rpb[s];
    }
    __syncthreads();

    // ---- 5 fused iterations ---------------------------------------------
    for (int k = 1; k <= 5; ++k) {
        // u-phase over li,lj in [k, REG-2k]  (valid cone of u^k)
        const int lo = k, hi_u = REG - 2 * k;
        {
            bool cm[SLOTS];
            int  ax[SLOTS];
            #pragma unroll
            for (int s = 0; s < SLOTS; ++s) {
                int li = lis[s], lj = ljs[s];
                cm[s] = (li >= lo) & (li <= hi_u) & (lj >= lo) & (lj <= hi_u);
                ax[s] = cm[s] ? (tid + s * TPB) : SAFE_U;
            }
            // hoisted load cluster: 12 ds_read_b64 in flight
            float2 pal[SLOTS], par[SLOTS], pbt[SLOTS], pbb[SLOTS];
            #pragma unroll
            for (int s = 0; s < SLOTS; ++s) {
                pal[s] = spa[ax[s] - 1];
                par[s] = spa[ax[s] + 1];
                pbt[s] = spb[ax[s] - REG];
                pbb[s] = spb[ax[s] + REG];
            }
            #pragma unroll
            for (int s = 0; s < SLOTS; ++s) {
                float2 uv = ruv[s];
                float rho = rrc[s] + rgx[s] * uv.x + rgy[s] * uv.y;
                // th>0 always (nm>=EPS, tl>0): rho==0 takes inside branch,
                // copysignf(tl,0) never selected -> sign(0)=0 handled.
                float d = (fabsf(rho) < rth[s]) ? rho * rnv[s] : copysignf(tl, rho);
                float v1 = uv.x - d * rgx[s];
                float v2 = uv.y - d * rgy[s];
                float2 pac = rpa[s], pbc = rpb[s];
                float div1 = wx0 * pal[s].x + wx1 * pac.x + wx2 * par[s].x
                           + wy0 * pbt[s].x + wy1 * pbc.x + wy2 * pbb[s].x;
                float div2 = wx0 * pal[s].y + wx1 * pac.y + wx2 * par[s].y
                           + wy0 * pbt[s].y + wy1 * pbc.y + wy2 * pbb[s].y;
                float nu1 = v1 + theta * div1;
                float nu2 = v2 + theta * div2;
                if (!inb[s]) { nu1 = 0.f; nu2 = 0.f; }   // zero-padding
                float2 nuv = make_float2(nu1, nu2);
                if (cm[s]) { ruv[s] = nuv; su[tid + s * TPB] = nuv; }
            }
        }
        __syncthreads();
        if (phase == 2 && k == 5) break;   // 20th p-update is dead code

        // p-phase over li,lj in [k, REG-1-2k]  (valid cone of p^k)
        const int hi_p = REG - 1 - 2 * k;
        {
            bool cm[SLOTS];
            int  ax[SLOTS];
            #pragma unroll
            for (int s = 0; s < SLOTS; ++s) {
                int li = lis[s], lj = ljs[s];
                cm[s] = (li >= lo) & (li <= hi_p) & (lj >= lo) & (lj <= hi_p);
                ax[s] = cm[s] ? (tid + s * TPB) : SAFE_P;
            }
            // hoisted load cluster: 6 ds_read_b64 in flight
            float2 uR[SLOTS], uB[SLOTS];
            #pragma unroll
            for (int s = 0; s < SLOTS; ++s) {
                uR[s] = su[ax[s] + 1];
                uB[s] = su[ax[s] + REG];
            }
            #pragma unroll
            for (int s = 0; s < SLOTS; ++s) {
                float2 uc = ruv[s];
                float gu1x = uR[s].x - uc.x, gu1y = uB[s].x - uc.x;
                float gu2x = uR[s].y - uc.y, gu2y = uB[s].y - uc.y;
                float d1 = 1.f + r * (fabsf(gu1x) + fabsf(gu1y));
                float id1 = __builtin_amdgcn_rcpf(d1);
                float np11 = (rpa[s].x + r * gu1x) * id1;
                float np12 = (rpb[s].x + r * gu1y) * id1;
                float d2 = 1.f + r * (fabsf(gu2x) + fabsf(gu2y));
                float id2 = __builtin_amdgcn_rcpf(d2);
                float np21 = (rpa[s].y + r * gu2x) * id2;
                float np22 = (rpb[s].y + r * gu2y) * id2;
                if (!inb[s]) { np11 = 0.f; np12 = 0.f; np21 = 0.f; np22 = 0.f; }
                float2 npa = make_float2(np11, np21);
                float2 npb = make_float2(np12, np22);
                if (cm[s]) {
                    rpa[s] = npa; rpb[s] = npb;
                    spa[tid + s * TPB] = npa; spb[tid + s * TPB] = npb;
                }
            }
        }
        __syncthreads();
    }

    // ---- epilogue --------------------------------------------------------
    if (phase != 2) {
        // write back interior [0,31]^2 (li,lj in [6,37]) from mirrors
        #pragma unroll
        for (int s = 0; s < SLOTS; ++s) {
            int li = lis[s], lj = ljs[s];
            if (li < HALO_L || li >= HALO_L + T || lj < HALO_L || lj >= HALO_L + T) continue;
            int gl = gofs[s];
            ug[gbase + gl] = ruv[s];
            pg[gbase + gl] = make_float4(rpa[s].x, rpa[s].y, rpb[s].x, rpb[s].y);
        }
    } else {
        // fused avgpool(3,1,1, /9 always); u^5 valid on [-1,32] — exact fit
        const float inv9 = 1.f / 9.f;
        #pragma unroll
        for (int s = 0; s < SLOTS; ++s) {
            int idx = tid + s * TPB;
            int li = lis[s], lj = ljs[s];
            if (li < HALO_L || li >= HALO_L + T || lj < HALO_L || lj >= HALO_L + T) continue;
            float2 a0 = su[idx - REG - 1], a1 = su[idx - REG], a2 = su[idx - REG + 1];
            float2 b0 = su[idx - 1],       b1 = su[idx],       b2 = su[idx + 1];
            float2 c0 = su[idx + REG - 1], c1 = su[idx + REG], c2 = su[idx + REG + 1];
            float s1 = a0.x + a1.x + a2.x + b0.x + b1.x + b2.x + c0.x + c1.x + c2.x;
            float s2 = a0.y + a1.y + a2.y + b0.y + b1.y + b2.y + c0.y + c1.y + c2.y;
            int gl = gofs[s];
            out[(size_t)bimg * 2 * HW + gl]      = s1 * inv9;
            out[(size_t)bimg * 2 * HW + HW + gl] = s2 * inv9;
        }
    }
}

// --------------------------------------------------------------- launch ---
extern "C" void kernel_launch(void* const* d_in, const int* in_sizes, int n_in,
                              void* d_out, int out_size, void* d_ws, size_t ws_size,
                              hipStream_t stream) {
    const float* x     = (const float*)d_in[0];
    const float* lam   = (const float*)d_in[1];
    const float* tau   = (const float*)d_in[2];
    const float* theta = (const float*)d_in[3];
    const float* wx    = (const float*)d_in[4];
    const float* wy    = (const float*)d_in[5];
    float* out = (float*)d_out;

    float*  ws = (float*)d_ws;
    float2* ug = (float2*)ws;                         // 8 MB
    float4* pg = (float4*)(ws + (size_t)2 * NTOT);    // 16 MB

    for (int c = 0; c < 4; ++c) {
        int phase = (c == 0) ? 0 : (c == 3) ? 2 : 1;
        k_fused<<<dim3(NBLK), dim3(TPB), 0, stream>>>(
            x, ug, pg, lam, tau, theta, wx, wy, out, phase);
    }
}

// Round 8
// 178.981 us; speedup vs baseline: 1.2990x; 1.2990x over previous
//
#include <hip/hip_runtime.h>

// TV-L1 optical flow, B=4, 512x512, 20 iters — temporal blocking (ghost zones)
// R13: R10 geometry (T=32, REG=48, LDS 55.3 KB -> 2 blocks/CU) with TPB
// 1024. 2 blocks x 1024 = 2048 threads/CU = the HW cap = 8 waves/SIMD
// (R10: 6). Body is the R9 guarded structure verbatim (R12's branchless
// rewrite regressed: select machinery cost ~2.4us, loads were already
// TLP-hidden; R6-R8 lesson: body perturbations risk IR-level array
// demotion — watch VGPR_Count/FETCH_SIZE). SLOTS=3: slots 0,1 full,
// slot 2 has 256 active threads = exactly 4 waves -> the idx<NPX guard
// is wave-uniform, no divergence. VGPR must stay <=64 for 8 waves/SIMD
// (same body compiled to 52 at SLOTS=5).
//   LDS: su=(u1,u2), spa=(p11,p21), spb=(p12,p22), 3 x 2304 x 8B = 55.3 KB.
// Halo L=6/R=10 (48x48 region per 32x32 tile). Zero-padding reproduced by
// forcing u=p=0 on out-of-image pixels. Last kernel skips the dead 20th
// p-update and fuses the 3x3 avgpool.

#define HH 512
#define WW 512
#define BB 4
constexpr int HW   = HH * WW;
constexpr int NTOT = BB * HW;
constexpr float EPS = 1e-8f;

#define T 32          // output tile edge
#define HALO_L 6      // left/top halo
#define REG 48        // region edge = 32 + 6 + 10
#define NPX (REG * REG)   // 2304
#define TPB 1024
#define SLOTS 3       // 3*1024 = 3072 >= 2304; slot 2: 4 active waves
#define NBLK 1024     // 4 images x 16x16 tiles
#define XR 50         // x1 staging edge (region + 1-ring for 3x3 gradient)
#define XN (XR * XR)  // 2500 <= 4608 floats available in spa; 3*1024 >= 2500

// phase: 0 = first (u,p zero-init, write back), 1 = middle (load, write
// back), 2 = last (load, 5 u-phases + 4 p-phases, fused avgpool -> out).
__global__ __launch_bounds__(TPB, 1) void k_fused(
    const float* __restrict__ x,
    float2* __restrict__ ug, float4* __restrict__ pg,
    const float* __restrict__ lam_p, const float* __restrict__ tau_p,
    const float* __restrict__ theta_p,
    const float* __restrict__ wxp, const float* __restrict__ wyp,
    float* __restrict__ out, int phase)
{
    __shared__ float2 su[NPX];    // (u1,u2)
    __shared__ float2 spa[NPX];   // (p11,p21); doubles as x1 staging buffer
    __shared__ float2 spb[NPX];   // (p12,p22)   -> 55.3 KB total

    const int tid  = threadIdx.x;
    const int blk  = blockIdx.x;
    const int bimg = blk >> 8;
    const int t    = blk & 255;
    const int gi0  = (t >> 4) * T;
    const int gj0  = (t & 15) * T;

    const float lam = lam_p[0], theta = theta_p[0];
    const float r   = tau_p[0] / theta;
    const float tl  = theta * lam;
    const float wx0 = wxp[0], wx1 = wxp[1], wx2 = wxp[2];
    const float wy0 = wyp[0], wy1 = wyp[1], wy2 = wyp[2];

    const int gbase = bimg * HW;
    const float* x0p = x + (size_t)bimg * 2 * HW;
    const float* x1p = x0p + HW;

    int  lis[SLOTS], ljs[SLOTS], gofs[SLOTS];
    bool inb[SLOTS];
    float2 ruv[SLOTS], rpa[SLOTS], rpb[SLOTS];  // own-pixel mirrors
    float  x0v[SLOTS];

    // ---- pass 1: stage x1 into spa-as-float; precompute per-slot indices;
    //      issue state loads early (consumed in pass 3, overlap statics) ----
    #pragma unroll
    for (int s = 0; s < SLOTS; ++s) {
        int idx = tid + s * TPB;
        if (idx < XN) {
            int li = idx / XR, lj = idx - li * XR;
            int gi = gi0 + li - (HALO_L + 1), gj = gj0 + lj - (HALO_L + 1);
            bool in = ((unsigned)gi < HH) & ((unsigned)gj < WW);
            ((float*)spa)[idx] = in ? x1p[gi * WW + gj] : 0.f;
        }
        if (idx < NPX) {
            int li = idx / REG, lj = idx - li * REG;
            lis[s] = li; ljs[s] = lj;
            int gi = gi0 + li - HALO_L, gj = gj0 + lj - HALO_L;
            bool in = ((unsigned)gi < HH) & ((unsigned)gj < WW);
            inb[s] = in;
            int gl = gi * WW + gj;            // valid only when in
            gofs[s] = gl;
            float2 uv = make_float2(0.f, 0.f);
            float4 p4 = make_float4(0.f, 0.f, 0.f, 0.f);
            float xv = 0.f;
            if (in) {
                xv = x0p[gl];
                if (phase != 0) {
                    uv = ug[gbase + gl];
                    p4 = pg[gbase + gl];
                }
            }
            x0v[s] = xv;
            ruv[s] = uv;
            rpa[s] = make_float2(p4.x, p4.y);
            rpb[s] = make_float2(p4.z, p4.w);
        }
    }
    __syncthreads();

    // ---- pass 2: statics (gx,gy,rc,th,1/nm) from staged x1 ---------------
    float rgx[SLOTS], rgy[SLOTS], rrc[SLOTS], rth[SLOTS], rnv[SLOTS];
    const float* stg = (const float*)spa;
    #pragma unroll
    for (int s = 0; s < SLOTS; ++s) {
        int idx = tid + s * TPB;
        if (idx < NPX) {
            int sc = (lis[s] + 1) * XR + (ljs[s] + 1);
            float a00 = stg[sc - XR - 1], a01 = stg[sc - XR], a02 = stg[sc - XR + 1];
            float a10 = stg[sc - 1],      a11 = stg[sc],      a12 = stg[sc + 1];
            float a20 = stg[sc + XR - 1], a21 = stg[sc + XR], a22 = stg[sc + XR + 1];
            const float c6 = 1.f / 6.f;
            float gxv = c6 * (-a00 + a02 - 2.f * a10 + 2.f * a12 - a20 + a22);
            float gyv = c6 * (-a00 - 2.f * a01 - a02 + a20 + 2.f * a21 + a22);
            float nm  = gxv * gxv + gyv * gyv + EPS;
            rgx[s] = gxv; rgy[s] = gyv;
            rrc[s] = a11 - x0v[s];           // zero-padded conv semantics held
            rth[s] = tl * nm;
            rnv[s] = __builtin_amdgcn_rcpf(nm);
        }
    }
    __syncthreads();

    // ---- pass 3: fill LDS state (overwrites staging) ---------------------
    #pragma unroll
    for (int s = 0; s < SLOTS; ++s) {
        int idx = tid + s * TPB;
        if (idx < NPX) {
            su[idx]  = ruv[s];
            spa[idx] = rpa[s];
            spb[idx] = rpb[s];
        }
    }
    __syncthreads();

    // ---- 5 fused iterations ---------------------------------------------
    for (int k = 1; k <= 5; ++k) {
        // u-phase over li,lj in [k, REG-2k]  (valid cone of u^k)
        const int lo = k, hi_u = REG - 2 * k;
        #pragma unroll
        for (int s = 0; s < SLOTS; ++s) {
            int idx = tid + s * TPB;
            if (idx >= NPX) continue;
            int li = lis[s], lj = ljs[s];
            if (li < lo || li > hi_u || lj < lo || lj > hi_u) continue;
            float2 uv = ruv[s];
            float rho = rrc[s] + rgx[s] * uv.x + rgy[s] * uv.y;
            // th>0 always (nm>=EPS, tl>0), so rho==0 takes the inside branch:
            // copysignf(tl,0) is never selected -> sign(0)=0 handled.
            float d = (fabsf(rho) < rth[s]) ? rho * rnv[s] : copysignf(tl, rho);
            float v1 = uv.x - d * rgx[s];
            float v2 = uv.y - d * rgy[s];
            float2 pal = spa[idx - 1],   par = spa[idx + 1];
            float2 pbt = spb[idx - REG], pbb = spb[idx + REG];
            float2 pac = rpa[s],         pbc = rpb[s];
            float div1 = wx0 * pal.x + wx1 * pac.x + wx2 * par.x
                       + wy0 * pbt.x + wy1 * pbc.x + wy2 * pbb.x;
            float div2 = wx0 * pal.y + wx1 * pac.y + wx2 * par.y
                       + wy0 * pbt.y + wy1 * pbc.y + wy2 * pbb.y;
            float nu1 = v1 + theta * div1;
            float nu2 = v2 + theta * div2;
            if (!inb[s]) { nu1 = 0.f; nu2 = 0.f; }   // zero-padding semantics
            float2 nuv = make_float2(nu1, nu2);
            ruv[s] = nuv; su[idx] = nuv;
        }
        __syncthreads();
        if (phase == 2 && k == 5) break;   // 20th p-update is dead code

        // p-phase over li,lj in [k, REG-1-2k]  (valid cone of p^k)
        const int hi_p = REG - 1 - 2 * k;
        #pragma unroll
        for (int s = 0; s < SLOTS; ++s) {
            int idx = tid + s * TPB;
            if (idx >= NPX) continue;
            int li = lis[s], lj = ljs[s];
            if (li < lo || li > hi_p || lj < lo || lj > hi_p) continue;
            float2 uc = ruv[s];
            float2 uR = su[idx + 1];
            float2 uB = su[idx + REG];
            float gu1x = uR.x - uc.x, gu1y = uB.x - uc.x;
            float gu2x = uR.y - uc.y, gu2y = uB.y - uc.y;
            float d1 = 1.f + r * (fabsf(gu1x) + fabsf(gu1y));
            float id1 = __builtin_amdgcn_rcpf(d1);
            float np11 = (rpa[s].x + r * gu1x) * id1;
            float np12 = (rpb[s].x + r * gu1y) * id1;
            float d2 = 1.f + r * (fabsf(gu2x) + fabsf(gu2y));
            float id2 = __builtin_amdgcn_rcpf(d2);
            float np21 = (rpa[s].y + r * gu2x) * id2;
            float np22 = (rpb[s].y + r * gu2y) * id2;
            if (!inb[s]) { np11 = 0.f; np12 = 0.f; np21 = 0.f; np22 = 0.f; }
            float2 npa = make_float2(np11, np21);
            float2 npb = make_float2(np12, np22);
            rpa[s] = npa; rpb[s] = npb;
            spa[idx] = npa; spb[idx] = npb;
        }
        __syncthreads();
    }

    // ---- epilogue --------------------------------------------------------
    if (phase != 2) {
        // write back interior [0,31]^2 (li,lj in [6,37]) from mirrors
        #pragma unroll
        for (int s = 0; s < SLOTS; ++s) {
            int idx = tid + s * TPB;
            if (idx >= NPX) continue;
            int li = lis[s], lj = ljs[s];
            if (li < HALO_L || li >= HALO_L + T || lj < HALO_L || lj >= HALO_L + T) continue;
            int gl = gofs[s];
            ug[gbase + gl] = ruv[s];
            pg[gbase + gl] = make_float4(rpa[s].x, rpa[s].y, rpb[s].x, rpb[s].y);
        }
    } else {
        // fused avgpool(3,1,1, /9 always); u^5 valid on [-1,32] — exact fit
        const float inv9 = 1.f / 9.f;
        #pragma unroll
        for (int s = 0; s < SLOTS; ++s) {
            int idx = tid + s * TPB;
            if (idx >= NPX) continue;
            int li = lis[s], lj = ljs[s];
            if (li < HALO_L || li >= HALO_L + T || lj < HALO_L || lj >= HALO_L + T) continue;
            float2 a0 = su[idx - REG - 1], a1 = su[idx - REG], a2 = su[idx - REG + 1];
            float2 b0 = su[idx - 1],       b1 = su[idx],       b2 = su[idx + 1];
            float2 c0 = su[idx + REG - 1], c1 = su[idx + REG], c2 = su[idx + REG + 1];
            float s1 = a0.x + a1.x + a2.x + b0.x + b1.x + b2.x + c0.x + c1.x + c2.x;
            float s2 = a0.y + a1.y + a2.y + b0.y + b1.y + b2.y + c0.y + c1.y + c2.y;
            int gl = gofs[s];
            out[(size_t)bimg * 2 * HW + gl]      = s1 * inv9;
            out[(size_t)bimg * 2 * HW + HW + gl] = s2 * inv9;
        }
    }
}

// --------------------------------------------------------------- launch ---
extern "C" void kernel_launch(void* const* d_in, const int* in_sizes, int n_in,
                              void* d_out, int out_size, void* d_ws, size_t ws_size,
                              hipStream_t stream) {
    const float* x     = (const float*)d_in[0];
    const float* lam   = (const float*)d_in[1];
    const float* tau   = (const float*)d_in[2];
    const float* theta = (const float*)d_in[3];
    const float* wx    = (const float*)d_in[4];
    const float* wy    = (const float*)d_in[5];
    float* out = (float*)d_out;

    float*  ws = (float*)d_ws;
    float2* ug = (float2*)ws;                         // 8 MB
    float4* pg = (float4*)(ws + (size_t)2 * NTOT);    // 16 MB

    for (int c = 0; c < 4; ++c) {
        int phase = (c == 0) ? 0 : (c == 3) ? 2 : 1;
        k_fused<<<dim3(NBLK), dim3(TPB), 0, stream>>>(
            x, ug, pg, lam, tau, theta, wx, wy, out, phase);
    }
}